// Round 4
// baseline (5369.591 us; speedup 1.0000x reference)
//
#include <hip/hip_runtime.h>

typedef unsigned short u16;
typedef unsigned int u32;
using u16x4 = __attribute__((ext_vector_type(4))) u16;
using u16x8 = __attribute__((ext_vector_type(8))) u16;
using bf16x8 = __attribute__((ext_vector_type(8))) __bf16;
using f32x4 = __attribute__((ext_vector_type(4))) float;

#define B_ 8
#define T_ 2048
#define C_ 768
#define E_ 8
#define K_ 2
#define H_ 3072
#define CAP_ 640
#define M_ (B_ * CAP_) /* 5120 rows per expert */
#define HC_ 1024       /* H chunk: S_chunk = E*M*HC bf16 = 83.9 MB */
#define NCHUNK_ (H_ / HC_)
#define OVF_MAX_ 32768

__device__ __forceinline__ u16 f2bf(float x) {
  u32 u = __float_as_uint(x);
  u32 r = (u + 0x7FFFu + ((u >> 16) & 1u)) >> 16;  // RNE
  return (u16)r;
}
__device__ __forceinline__ float bf2f(u16 v) { return __uint_as_float(((u32)v) << 16); }

__device__ __forceinline__ void gl_lds16(const u16* g, u16* l) {
  __builtin_amdgcn_global_load_lds((const __attribute__((address_space(1))) u32*)g,
                                   (__attribute__((address_space(3))) u32*)l, 16, 0, 0);
}
__device__ __forceinline__ bf16x8 ldfrag(const u16* p) {
  return __builtin_bit_cast(bf16x8, *(const u16x8*)p);
}

// ---------- weight fp32 -> bf16 transpose:  in [E][R][Cc] -> out [E][Cc][R] ----------
__global__ void wconv_transpose(const float* __restrict__ in, u16* __restrict__ out,
                                int R, int Cc) {
  __shared__ float tile[32][33];
  const float* inE = in + (size_t)blockIdx.z * R * Cc;
  u16* outE = out + (size_t)blockIdx.z * R * Cc;
  int tx = threadIdx.x & 31, ty = threadIdx.x >> 5;  // 32 x 8
  int r0 = blockIdx.y * 32, c0 = blockIdx.x * 32;
#pragma unroll
  for (int j = 0; j < 4; j++)
    tile[ty + j * 8][tx] = inE[(size_t)(r0 + ty + j * 8) * Cc + (c0 + tx)];
  __syncthreads();
#pragma unroll
  for (int j = 0; j < 4; j++)
    outE[(size_t)(c0 + ty + j * 8) * R + (r0 + tx)] = f2bf(tile[tx][ty + j * 8]);
}

// ---------- router: logits, softmax, top-2 (fp64 accumulate; tie -> lower index) ----------
__global__ void router_kernel(const float* __restrict__ x, const float* __restrict__ wr,
                              const float* __restrict__ br, float* __restrict__ tkp,
                              int* __restrict__ tki) {
  int bt = (blockIdx.x << 2) | (threadIdx.x >> 6);  // token index b*T+t
  int lane = threadIdx.x & 63;
  const float* xr = x + (size_t)bt * C_;
  double acc[E_];
#pragma unroll
  for (int e = 0; e < E_; e++) acc[e] = 0.0;
#pragma unroll
  for (int i = 0; i < C_ / 64; i++) {
    int c = lane + i * 64;
    float xv = xr[c];
    const float* w = wr + c * E_;
#pragma unroll
    for (int e = 0; e < E_; e++) acc[e] += (double)xv * (double)w[e];
  }
#pragma unroll
  for (int off = 32; off > 0; off >>= 1) {
#pragma unroll
    for (int e = 0; e < E_; e++) acc[e] += __shfl_xor(acc[e], off);
  }
  if (lane == 0) {
    double lg[E_];
#pragma unroll
    for (int e = 0; e < E_; e++) lg[e] = acc[e] + (double)br[e];
    int i0 = 0;
#pragma unroll
    for (int e = 1; e < E_; e++) if (lg[e] > lg[i0]) i0 = e;
    int i1 = (i0 == 0) ? 1 : 0;
#pragma unroll
    for (int e = 0; e < E_; e++) if (e != i0 && lg[e] > lg[i1]) i1 = e;
    double mx = lg[i0], s = 0.0, pv[E_];
#pragma unroll
    for (int e = 0; e < E_; e++) { pv[e] = exp(lg[e] - mx); s += pv[e]; }
    tkp[bt * 2 + 0] = (float)(pv[i0] / s);
    tkp[bt * 2 + 1] = (float)(pv[i1] / s);
    tki[bt * 2 + 0] = i0;
    tki[bt * 2 + 1] = i1;
  }
}

// ---------- slot positions: parallel 8-way counted scan, one block per b ----------
__global__ void pos_kernel(const int* __restrict__ tki, int* __restrict__ pos) {
  __shared__ int sc[256][9];  // +1 pad: avoid 8-way bank conflict
  int b = blockIdx.x;
  int tid = threadIdx.x;
  const int* tib = tki + (size_t)b * T_ * 2;
  int* pb = pos + (size_t)b * T_ * 2;
  int ids[16];
  int cnt[E_];
#pragma unroll
  for (int e = 0; e < E_; e++) cnt[e] = 0;
#pragma unroll
  for (int j = 0; j < 16; j++) {
    int i = tid * 16 + j;
    int k = i >> 11, t = i & (T_ - 1);  // k-major
    int id = tib[t * 2 + k];
    ids[j] = id;
#pragma unroll
    for (int e = 0; e < E_; e++) cnt[e] += (id == e);
  }
#pragma unroll
  for (int e = 0; e < E_; e++) sc[tid][e] = cnt[e];
  __syncthreads();
  for (int off = 1; off < 256; off <<= 1) {
    int v[E_];
    if (tid >= off) {
#pragma unroll
      for (int e = 0; e < E_; e++) v[e] = sc[tid - off][e];
    }
    __syncthreads();
    if (tid >= off) {
#pragma unroll
      for (int e = 0; e < E_; e++) sc[tid][e] += v[e];
    }
    __syncthreads();
  }
  int base[E_];
#pragma unroll
  for (int e = 0; e < E_; e++) base[e] = (tid > 0) ? sc[tid - 1][e] : 0;
#pragma unroll
  for (int j = 0; j < 16; j++) {
    int i = tid * 16 + j;
    int k = i >> 11, t = i & (T_ - 1);
    int id = ids[j];
    int p = 0;
#pragma unroll
    for (int e = 0; e < E_; e++) p += (id == e) ? base[e] : 0;
    pb[t * 2 + k] = p;
#pragma unroll
    for (int e = 0; e < E_; e++) base[e] += (id == e);
  }
}

// ---------- clear inverse map + overflow counter (must precede dispatch) ----------
__global__ void clear_kernel(int* __restrict__ invt, int* __restrict__ ovfCnt) {
  int i = blockIdx.x * 256 + threadIdx.x;  // grid covers exactly E_*M_
  invt[i] = -1;
  if (i == 0) *ovfCnt = 0;
}

// ---------- dispatch: x row -> bf16 expert buffer [E][M_][C_] + inverse map + out init ----------
__global__ void dispatch_kernel(const float* __restrict__ x, const int* __restrict__ tki,
                                const int* __restrict__ pos, const float* __restrict__ tkp,
                                const float* __restrict__ bp, u16* __restrict__ Xd,
                                int* __restrict__ invt, int* __restrict__ ovfCnt,
                                int2* __restrict__ ovf, float* __restrict__ out) {
  int gw = (blockIdx.x << 2) | (threadIdx.x >> 6);  // (b*T+t)*2 + k
  int lane = threadIdx.x & 63;
  int bt = gw >> 1;
  int b = bt >> 11;
  // k==0 wave also initializes out[bt] = w0*bp[e0] + w1*bp[e1] (proj bias, pre-added)
  if ((gw & 1) == 0) {
    int e0 = tki[bt * 2], e1 = tki[bt * 2 + 1];
    float w0 = tkp[bt * 2], w1 = tkp[bt * 2 + 1];
    const f32x4* b0 = (const f32x4*)(bp + (size_t)e0 * C_);
    const f32x4* b1 = (const f32x4*)(bp + (size_t)e1 * C_);
    f32x4* orow = (f32x4*)(out + (size_t)bt * C_);
#pragma unroll
    for (int i = 0; i < 3; i++) {
      int c = lane + i * 64;
      orow[c] = w0 * b0[c] + w1 * b1[c];
    }
  }
  int e = tki[gw];
  int p = pos[gw];
  if (p >= CAP_) {  // capacity drop: record for exact clamp-gather handling
    if (lane == 0) {
      int idx = atomicAdd(ovfCnt, 1);
      if (idx < OVF_MAX_) ovf[idx] = make_int2(bt, gw & 1);
    }
    return;
  }
  size_t row = (size_t)e * M_ + (size_t)b * CAP_ + p;
  if (lane == 0) invt[row] = gw;  // owner (token,slot) of this expert row
  const f32x4* src = (const f32x4*)(x + (size_t)bt * C_);
  u16* dst = Xd + row * C_;
#pragma unroll
  for (int i = 0; i < 3; i++) {
    f32x4 v = src[lane + i * 64];
    u16x4 o;
    o.x = f2bf(v.x); o.y = f2bf(v.y); o.z = f2bf(v.z); o.w = f2bf(v.w);
    *(u16x4*)(dst + (size_t)(lane + i * 64) * 4) = o;
  }
}

// ---------- GEMM1: S_chunk = silu((X@Wfc+bfc)*(X@Wg+bg)) ----------
// BM=256, BN=128, BK=32, 512 thr / 8 waves (4M x 2N), per-wave 64x64 dual-B.
// 2 LDS bufs (64 KB) -> 2 blocks/CU = 4 waves/SIMD, two independent barrier domains.
// T3-min skeleton: [sync(drain)] -> stage(kt+1) -> ds_read(kt) -> MFMA(kt).
// grid = E * 20 * 8 = 1280 blocks
__global__ __launch_bounds__(512, 4) void gemm_fc_gate(
    const u16* __restrict__ Xd, const u16* __restrict__ WfcT, const u16* __restrict__ WgT,
    const float* __restrict__ bfc, const float* __restrict__ bg, u16* __restrict__ S,
    int hc) {
  __shared__ __align__(16) u16 Asm[2][256 * 32];
  __shared__ __align__(16) u16 B1sm[2][128 * 32];
  __shared__ __align__(16) u16 B2sm[2][128 * 32];
  const int NWG = E_ * 20 * 8;  // 1280
  int bid0 = blockIdx.x;
  int bid = (bid0 & 7) * (NWG >> 3) + (bid0 >> 3);  // XCD swizzle (NWG%8==0)
  int e = bid / 160;
  int t = bid % 160;
  int tm = t / 8, tn = t % 8;
  int tid = threadIdx.x;
  int lane = tid & 63, wv = tid >> 6;  // 8 waves
  int wm = wv >> 1, wn = wv & 1;       // 4M x 2N
  int lr = lane & 15, quad = lane >> 4;

  const u16* XdE = Xd + (size_t)e * M_ * C_;
  const u16* B1E = WfcT + ((size_t)e * H_ + (size_t)hc * HC_) * C_;  // [H][C]
  const u16* B2E = WgT + ((size_t)e * H_ + (size_t)hc * HC_) * C_;

  // staging: per thread 4 x 16B. A[256][32]: 2 loads; B1,B2[128][32]: 1 each.
  // source col pre-swizzled (chunk ^ row&3) so linear DMA lands XOR-swizzled.
  int r4 = lane >> 2, sl = lane & 3;
  int scol = (sl ^ (r4 & 3)) * 8;
  const u16* gA0 = XdE + (size_t)(tm * 256 + wv * 16 + r4) * C_ + scol;
  const u16* gA1 = gA0 + (size_t)128 * C_;
  const u16* gB1 = B1E + (size_t)(tn * 128 + wv * 16 + r4) * C_ + scol;
  const u16* gB2 = B2E + (size_t)(tn * 128 + wv * 16 + r4) * C_ + scol;
  int ab = wv * 512;  // wave-uniform LDS base (u16 units); lane*8 added by HW

  f32x4 acc1[4][4], acc2[4][4];
#pragma unroll
  for (int i = 0; i < 4; i++)
#pragma unroll
    for (int j = 0; j < 4; j++) {
      acc1[i][j] = (f32x4){0.f, 0.f, 0.f, 0.f};
      acc2[i][j] = (f32x4){0.f, 0.f, 0.f, 0.f};
    }

  const int NK = C_ / 32;  // 24

  // prologue: stage tile 0 -> buf 0
  gl_lds16(gA0, &Asm[0][ab]);
  gl_lds16(gA1, &Asm[0][ab + 4096]);
  gl_lds16(gB1, &B1sm[0][ab]);
  gl_lds16(gB2, &B2sm[0][ab]);

  int cur = 0;
  for (int kt = 0; kt < NK; kt++) {
    __syncthreads();  // drain: tile kt resident; all waves done reading buf cur^1
    if (kt + 1 < NK) {  // stage kt+1 into the other buffer; full step of compute below
      int ko = (kt + 1) * 32;
      int nb = cur ^ 1;
      gl_lds16(gA0 + ko, &Asm[nb][ab]);
      gl_lds16(gA1 + ko, &Asm[nb][ab + 4096]);
      gl_lds16(gB1 + ko, &B1sm[nb][ab]);
      gl_lds16(gB2 + ko, &B2sm[nb][ab]);
    }
    int rq = (quad ^ (lr & 3)) * 8;  // swizzled read slot (row&3 == lr&3)
    bf16x8 af[4], b1f[4], b2f[4];
#pragma unroll
    for (int i = 0; i < 4; i++)
      af[i] = ldfrag(&Asm[cur][(wm * 64 + i * 16 + lr) * 32 + rq]);
#pragma unroll
    for (int j = 0; j < 4; j++) {
      b1f[j] = ldfrag(&B1sm[cur][(wn * 64 + j * 16 + lr) * 32 + rq]);
      b2f[j] = ldfrag(&B2sm[cur][(wn * 64 + j * 16 + lr) * 32 + rq]);
    }
    __builtin_amdgcn_s_setprio(1);
#pragma unroll
    for (int j = 0; j < 4; j++)
#pragma unroll
      for (int i = 0; i < 4; i++) {
        acc1[i][j] = __builtin_amdgcn_mfma_f32_16x16x32_bf16(af[i], b1f[j], acc1[i][j], 0, 0, 0);
        acc2[i][j] = __builtin_amdgcn_mfma_f32_16x16x32_bf16(af[i], b2f[j], acc2[i][j], 0, 0, 0);
      }
    __builtin_amdgcn_s_setprio(0);
    cur ^= 1;
  }

  u16* Se = S + (size_t)e * M_ * HC_;
  const float* bfcE = bfc + (size_t)e * H_ + (size_t)hc * HC_;
  const float* bgE = bg + (size_t)e * H_ + (size_t)hc * HC_;
  int col0 = tn * 128 + wn * 64 + lr;
  int row0 = tm * 256 + wm * 64 + quad * 4;
#pragma unroll
  for (int j = 0; j < 4; j++) {
    int col = col0 + j * 16;
    float bf_ = bfcE[col], bg_ = bgE[col];
#pragma unroll
    for (int i = 0; i < 4; i++) {
      int row = row0 + i * 16;
#pragma unroll
      for (int r = 0; r < 4; r++) {
        float h = acc1[i][j][r] + bf_;
        float g = acc2[i][j][r] + bg_;
        float z = h * g;
        float sv = z / (1.f + __expf(-z));  // silu
        Se[(size_t)(row + r) * HC_ + col] = f2bf(sv);
      }
    }
  }
}

// ---------- GEMM2: partial O scatter-added into out ----------
// BM=256, BN=128, BK=32, 256 thr / 4 waves (2M x 2N), per-wave 128x64 (FLOP/B 2x).
// LDS 48 KB -> 3 blocks/CU. grid = E * 20 * 6 = 960 blocks.
__global__ __launch_bounds__(256, 3) void gemm_proj_scatter(
    const u16* __restrict__ S, const u16* __restrict__ WpT,
    const int* __restrict__ invt, const float* __restrict__ tkp,
    const int* __restrict__ tki, const int* __restrict__ ovfCnt,
    const int2* __restrict__ ovf, float* __restrict__ out, int hc) {
  __shared__ __align__(16) u16 Asm[2][256 * 32];
  __shared__ __align__(16) u16 Bsm[2][128 * 32];
  const int NWG = E_ * 20 * 6;  // 960
  int bid0 = blockIdx.x;
  int bid = (bid0 & 7) * (NWG >> 3) + (bid0 >> 3);
  int e = bid / 120;
  int t = bid % 120;
  int tm = t / 6, tn = t % 6;
  int tid = threadIdx.x;
  int lane = tid & 63, wv = tid >> 6;  // 4 waves
  int wm = wv >> 1, wn = wv & 1;       // 2M x 2N
  int lr = lane & 15, quad = lane >> 4;

  const u16* SE = S + (size_t)e * M_ * HC_;                      // [M][HC]
  const u16* BE = WpT + (size_t)e * C_ * H_ + (size_t)hc * HC_;  // [C][H]

  int r4 = lane >> 2, sl = lane & 3;
  int scol = (sl ^ (r4 & 3)) * 8;
  const u16* gA[4];
#pragma unroll
  for (int L = 0; L < 4; L++)
    gA[L] = SE + (size_t)(tm * 256 + L * 64 + wv * 16 + r4) * HC_ + scol;
  const u16* gB[2];
#pragma unroll
  for (int L = 0; L < 2; L++)
    gB[L] = BE + (size_t)(tn * 128 + L * 64 + wv * 16 + r4) * H_ + scol;
  int ab = wv * 512;

  f32x4 acc[8][4];
#pragma unroll
  for (int i = 0; i < 8; i++)
#pragma unroll
    for (int j = 0; j < 4; j++) acc[i][j] = (f32x4){0.f, 0.f, 0.f, 0.f};

  const int NK = HC_ / 32;  // 32

#pragma unroll
  for (int L = 0; L < 4; L++) gl_lds16(gA[L], &Asm[0][ab + L * 2048]);
#pragma unroll
  for (int L = 0; L < 2; L++) gl_lds16(gB[L], &Bsm[0][ab + L * 2048]);

  int cur = 0;
  for (int kt = 0; kt < NK; kt++) {
    __syncthreads();
    if (kt + 1 < NK) {
      int ko = (kt + 1) * 32;
      int nb = cur ^ 1;
#pragma unroll
      for (int L = 0; L < 4; L++) gl_lds16(gA[L] + ko, &Asm[nb][ab + L * 2048]);
#pragma unroll
      for (int L = 0; L < 2; L++) gl_lds16(gB[L] + ko, &Bsm[nb][ab + L * 2048]);
    }
    int rq = (quad ^ (lr & 3)) * 8;
    bf16x8 af[8], bf[4];
#pragma unroll
    for (int i = 0; i < 8; i++)
      af[i] = ldfrag(&Asm[cur][(wm * 128 + i * 16 + lr) * 32 + rq]);
#pragma unroll
    for (int j = 0; j < 4; j++)
      bf[j] = ldfrag(&Bsm[cur][(wn * 64 + j * 16 + lr) * 32 + rq]);
    __builtin_amdgcn_s_setprio(1);
#pragma unroll
    for (int j = 0; j < 4; j++)
#pragma unroll
      for (int i = 0; i < 8; i++)
        acc[i][j] = __builtin_amdgcn_mfma_f32_16x16x32_bf16(af[i], bf[j], acc[i][j], 0, 0, 0);
    __builtin_amdgcn_s_setprio(0);
    cur ^= 1;
  }

  // epilogue: weighted scatter-add into out (bias pre-added at dispatch)
  int col0 = tn * 128 + wn * 64 + lr;
  int row0 = tm * 256 + wm * 128 + quad * 4;
  const int* invtE = invt + e * M_;
#pragma unroll
  for (int i = 0; i < 8; i++) {
#pragma unroll
    for (int r = 0; r < 4; r++) {
      int re = row0 + i * 16 + r;
      int g = invtE[re];  // row-uniform per quad -> branch is quad-uniform
      if (g >= 0) {
        float w = tkp[g];
        float* orow = out + (size_t)(g >> 1) * C_;
#pragma unroll
        for (int j = 0; j < 4; j++)
          atomicAdd(orow + col0 + j * 16, w * acc[i][j][r]);
      }
    }
  }
  // dropped tokens gather clamped row CAP_-1 (jax clip semantics). The block whose
  // tile contains expert-row b2*CAP_+CAP_-1 adds that row's partial for matching
  // overflow entries. Owner lanes: local row = wm*128 + 7*16 + quad*4 + 3.
#pragma unroll
  for (int b2 = 0; b2 < B_; b2++) {
    int grow = b2 * CAP_ + (CAP_ - 1);
    if ((grow >> 8) == tm) {
      int local = grow & 255;
      if (quad == 3 && wm == (local >> 7)) {
        int nov = *ovfCnt;
        if (nov > OVF_MAX_) nov = OVF_MAX_;
        for (int o = 0; o < nov; o++) {
          int2 en = ovf[o];
          int gw2 = en.x * 2 + en.y;
          if (tki[gw2] == e && (en.x >> 11) == b2) {
            float w = tkp[gw2];
            float* orow = out + (size_t)en.x * C_;
#pragma unroll
            for (int j = 0; j < 4; j++)
              atomicAdd(orow + col0 + j * 16, w * acc[7][j][3]);
          }
        }
      }
    }
  }
}

extern "C" void kernel_launch(void* const* d_in, const int* in_sizes, int n_in,
                              void* d_out, int out_size, void* d_ws, size_t ws_size,
                              hipStream_t stream) {
  (void)in_sizes; (void)n_in; (void)out_size; (void)ws_size;
  const float* x = (const float*)d_in[0];
  const float* w_router = (const float*)d_in[1];
  const float* b_router = (const float*)d_in[2];
  const float* w_c_fc = (const float*)d_in[3];
  const float* b_c_fc = (const float*)d_in[4];
  const float* w_gate = (const float*)d_in[5];
  const float* b_gate = (const float*)d_in[6];
  const float* w_c_proj = (const float*)d_in[7];
  const float* b_c_proj = (const float*)d_in[8];
  float* out = (float*)d_out;

  char* p = (char*)d_ws;
  auto alloc = [&](size_t n) { char* r = p; p += (n + 255) & ~(size_t)255; return r; };
  const size_t WN = (size_t)E_ * C_ * H_;
  u16* WfcT = (u16*)alloc(WN * 2);
  u16* WgT = (u16*)alloc(WN * 2);
  u16* WpT = (u16*)alloc(WN * 2);
  u16* Xd = (u16*)alloc((size_t)E_ * M_ * C_ * 2);
  float* tkp = (float*)alloc((size_t)B_ * T_ * 2 * 4);
  int* tki = (int*)alloc((size_t)B_ * T_ * 2 * 4);
  int* pos = (int*)alloc((size_t)B_ * T_ * 2 * 4);
  int* invt = (int*)alloc((size_t)E_ * M_ * 4);
  int* ovfCnt = (int*)alloc(4);
  int2* ovf = (int2*)alloc((size_t)OVF_MAX_ * 8);
  u16* S = (u16*)alloc((size_t)E_ * M_ * HC_ * 2);
  // total ~260.9 MB; previous g=1 layout proved ws >= 271 MB, so this fits.

  dim3 blk(256);
  // weights -> bf16, transposed to [N][K]
  wconv_transpose<<<dim3(H_ / 32, C_ / 32, E_), blk, 0, stream>>>(w_c_fc, WfcT, C_, H_);
  wconv_transpose<<<dim3(H_ / 32, C_ / 32, E_), blk, 0, stream>>>(w_gate, WgT, C_, H_);
  wconv_transpose<<<dim3(C_ / 32, H_ / 32, E_), blk, 0, stream>>>(w_c_proj, WpT, H_, C_);

  router_kernel<<<dim3(B_ * T_ / 4), blk, 0, stream>>>(x, w_router, b_router, tkp, tki);
  pos_kernel<<<dim3(B_), blk, 0, stream>>>(tki, pos);
  clear_kernel<<<dim3(E_ * M_ / 256), blk, 0, stream>>>(invt, ovfCnt);
  dispatch_kernel<<<dim3(B_ * T_ * K_ / 4), blk, 0, stream>>>(x, tki, pos, tkp, b_c_proj,
                                                              Xd, invt, ovfCnt, ovf, out);

  // H-chunked grouped GEMMs: every dispatch spans all 8 experts
  for (int hc = 0; hc < NCHUNK_; hc++) {
    gemm_fc_gate<<<dim3(E_ * 20 * 8), dim3(512), 0, stream>>>(
        Xd, WfcT, WgT, b_c_fc, b_gate, S, hc);
    gemm_proj_scatter<<<dim3(E_ * 20 * 6), blk, 0, stream>>>(
        S, WpT, invt, tkp, tki, ovfCnt, ovf, out, hc);
  }
}